// Round 7
// baseline (143.264 us; speedup 1.0000x reference)
//
#include <hip/hip_runtime.h>
#include <hip/hip_bf16.h>
#include <stdint.h>

#define DEV __device__ __forceinline__

typedef unsigned short u16;
typedef unsigned int   u32;
typedef __attribute__((ext_vector_type(8))) short bf16x8;   // 8 bf16 = 4 VGPRs
typedef __attribute__((ext_vector_type(4))) float f32x4;
typedef __attribute__((ext_vector_type(4))) u32   u32x4;
typedef __attribute__((ext_vector_type(2))) u32   u32x2;

// ---- numeric helpers -------------------------------------------------------
DEV u16 f2bf(float f) {            // RNE f32 -> bf16
  u32 u = __builtin_bit_cast(u32, f);
  u = (u + 0x7fffu + ((u >> 16) & 1u)) >> 16;
  return (u16)u;
}
DEV float bf2f(u16 h) { return __builtin_bit_cast(float, (u32)h << 16); }
DEV u32 pk2(float a, float b) {    // pack 2 f32 -> 2 bf16 in one u32 (RNE)
  u32 x = __builtin_bit_cast(u32, a), y = __builtin_bit_cast(u32, b);
  x = (x + 0x7fffu + ((x >> 16) & 1u)) >> 16;
  y = (y + 0x7fffu + ((y >> 16) & 1u)) >> 16;
  return x | (y << 16);
}
DEV u32 cvtpk(float lo, float hi) {  // 1-instr RNE pack (same semantics as pk2)
  u32 r;
  asm("v_cvt_pk_bf16_f32 %0, %1, %2" : "=v"(r) : "v"(lo), "v"(hi));
  return r;
}
DEV f32x4 mfma16(bf16x8 a, bf16x8 b, f32x4 c) {
  return __builtin_amdgcn_mfma_f32_16x16x32_bf16(a, b, c, 0, 0, 0);
}
DEV void gload16(const void* g, void* l) {   // global -> LDS direct, 16B/lane
  __builtin_amdgcn_global_load_lds(
      (const __attribute__((address_space(1))) void*)g,
      (__attribute__((address_space(3))) void*)l, 16, 0, 0);
}

// ---- problem constants -----------------------------------------------------
// B=2 T=2048 DIM=1024 HEADS=16 HEAD_DIM=64; tokens = 4096
// workspace layout (bytes):
//  XB      0         x as bf16            [4096][1024]
//  WQKVT   8388608   Wqkv^T bf16          [3072][1024]
//  WPROJT  14680064  Wproj^T bf16         [1024][1024]
//  QKV     16777216  qkv bf16             [4096][3072]
//  QR      41943040  roped*scale Q bf16   [32][2048][64]
//  KR      50331648  roped K bf16         [32][2048][64]
//  VT      58720256  V^T bf16 KEY-PERMUTED [32][64][2048]
//  AO      67108864  attn out bf16        [4096][1024]
//  SIN     75497472  f32 [2048][32]
//  COS     75759616  f32 [2048][32]

// ---- prep kernels ----------------------------------------------------------
__global__ __launch_bounds__(256) void k_cvt_bf16(const float* __restrict__ in,
                                                  u16* __restrict__ out) {
  size_t i = ((size_t)blockIdx.x * 256 + threadIdx.x) * 8;
  float4 a = *(const float4*)(in + i);
  float4 b = *(const float4*)(in + i + 4);
  u32x4 o = { pk2(a.x, a.y), pk2(a.z, a.w), pk2(b.x, b.y), pk2(b.z, b.w) };
  *(u32x4*)(out + i) = o;
}

// W [1024][Ndim] f32 -> WT [Ndim][1024] bf16 (coalesced both sides via LDS)
__global__ __launch_bounds__(256) void k_transpose_cvt(const float* __restrict__ W,
                                                       u16* __restrict__ WT,
                                                       int Ndim) {
  int bk = blockIdx.x & 31;        // K/32 = 32
  int bn = blockIdx.x >> 5;
  int k0 = bk * 32, n0 = bn * 32;
  __shared__ float t[32][33];
  int tx = threadIdx.x & 31, ty = threadIdx.x >> 5; // ty 0..7
#pragma unroll
  for (int i = 0; i < 4; ++i)
    t[ty + 8 * i][tx] = W[(size_t)(k0 + ty + 8 * i) * Ndim + n0 + tx];
  __syncthreads();
#pragma unroll
  for (int i = 0; i < 4; ++i) {
    int n = ty + 8 * i;
    WT[(size_t)(n0 + n) * 1024 + k0 + tx] = f2bf(t[tx][n]);
  }
}

__global__ __launch_bounds__(256) void k_tables(const int* __restrict__ posp,
                                                float* __restrict__ sint,
                                                float* __restrict__ cost) {
  int i = blockIdx.x * 256 + threadIdx.x;   // 65536 = 2048*32
  int t = i >> 5, d = i & 31;
  float theta = exp2f(-(float)d * (13.2877123795494f / 32.0f));
  float ang = (float)(posp[0] + t) * theta;
  sint[i] = sinf(ang);
  cost[i] = cosf(ang);
}

// ---- GEMM: C[4096][N] = A[4096][1024] @ BT^T + bias ------------------------
// 128x128 tile, BK=32, 4 waves (2x2 of 64x64), mfma 16x16x32 bf16.
// Staging: global_load_lds width=16, linear LDS dest, swizzle applied on the
// GLOBAL source address (rule #21). Reads use the same XOR chunk swizzle.
// launch_bounds(256,3): 3 blocks/CU (VGPR cap 170 > ~120 used) for barrier
// drain overlap (m97 ran ~3 blocks/CU).
template <int N, bool OUTF32>
__global__ __launch_bounds__(256, 3) void k_gemm(const u16* __restrict__ A,
                                                 const u16* __restrict__ BT,
                                                 const float* __restrict__ bias,
                                                 void* __restrict__ Cout) {
  constexpr int K = 1024;
  int bm = blockIdx.x & 31;             // M/128 = 32
  int bn = blockIdx.x >> 5;
  int m0 = bm * 128, n0 = bn * 128;
  int tid = threadIdx.x, lane = tid & 63, w = tid >> 6;
  int g = lane >> 4, l15 = lane & 15;
  int wr = w >> 1, wc = w & 1;

  __shared__ u16 Alds[128 * 32];
  __shared__ u16 Blds[128 * 32];

  f32x4 acc[4][4] = {};

  int rowW = w * 16 + (lane >> 2);
  int cSrc = (lane & 3) ^ ((lane >> 3) & 3);
  const u16* Ag0 = A  + (size_t)(m0 + rowW) * K + cSrc * 8;
  const u16* Ag1 = A  + (size_t)(m0 + 64 + rowW) * K + cSrc * 8;
  const u16* Bg0 = BT + (size_t)(n0 + rowW) * K + cSrc * 8;
  const u16* Bg1 = BT + (size_t)(n0 + 64 + rowW) * K + cSrc * 8;
  char* AldsW0 = (char*)Alds + w * 1024;          // + lane*16 by HW
  char* AldsW1 = (char*)Alds + 4096 + w * 1024;
  char* BldsW0 = (char*)Blds + w * 1024;
  char* BldsW1 = (char*)Blds + 4096 + w * 1024;

  for (int k0 = 0; k0 < K; k0 += 32) {
    gload16(Ag0 + k0, AldsW0);
    gload16(Ag1 + k0, AldsW1);
    gload16(Bg0 + k0, BldsW0);
    gload16(Bg1 + k0, BldsW1);
    __syncthreads();                    // drains vmcnt (compiler-inserted)
    bf16x8 af[4], bf_[4];
#pragma unroll
    for (int m = 0; m < 4; ++m) {
      int r = wr * 64 + m * 16 + l15;
      af[m] = *(const bf16x8*)((const char*)Alds + r * 64 + ((g ^ ((r >> 1) & 3)) << 4));
    }
#pragma unroll
    for (int n = 0; n < 4; ++n) {
      int r = wc * 64 + n * 16 + l15;
      bf_[n] = *(const bf16x8*)((const char*)Blds + r * 64 + ((g ^ ((r >> 1) & 3)) << 4));
    }
#pragma unroll
    for (int m = 0; m < 4; ++m)
#pragma unroll
      for (int n = 0; n < 4; ++n)
        acc[m][n] = mfma16(af[m], bf_[n], acc[m][n]);
    __syncthreads();
  }

#pragma unroll
  for (int m = 0; m < 4; ++m) {
    int rowb = m0 + wr * 64 + m * 16 + 4 * g;
#pragma unroll
    for (int n = 0; n < 4; ++n) {
      int col = n0 + wc * 64 + n * 16 + l15;
      float bv = bias[col];
#pragma unroll
      for (int j = 0; j < 4; ++j) {
        float v = acc[m][n][j] + bv;
        if constexpr (OUTF32)
          ((float*)Cout)[(size_t)(rowb + j) * N + col] = v;
        else
          ((u16*)Cout)[(size_t)(rowb + j) * N + col] = f2bf(v);
      }
    }
  }
}

// ---- RoPE + head reshape + V transpose (key-permuted for PV b128 frags) ----
// VT key order within each 64-tile: key kk = 32*s2 + 16*b + 4*g + j stored at
// pos = 32*s2 + 8*g + 4*b + j, so each PV A-fragment (8 keys) is contiguous.
__global__ __launch_bounds__(256) void k_rope(const u16* __restrict__ qkv,
                                              const float* __restrict__ sint,
                                              const float* __restrict__ cost,
                                              u16* __restrict__ QR,
                                              u16* __restrict__ KR,
                                              u16* __restrict__ VT) {
  int bid = blockIdx.x;
  int bh = bid >> 5;                 // T/64 = 32 blocks per (b,h)
  int t0 = (bid & 31) * 64;
  int b = bh >> 4, h = bh & 15;
  int tid = threadIdx.x;

  int dp = tid & 31;
  int tt0 = tid >> 5;                 // 0..7
#pragma unroll
  for (int r = 0; r < 8; ++r) {
    int tl = r * 8 + tt0;
    int t = t0 + tl;
    int tok = b * 2048 + t;
    const u16* row = qkv + (size_t)tok * 3072;
    float sn = sint[t * 32 + dp], cs = cost[t * 32 + dp];

    u32 qq = *(const u32*)(row + h * 64 + 2 * dp);
    float x1 = bf2f((u16)qq), x2 = bf2f((u16)(qq >> 16));
    u16* qo = QR + ((size_t)bh * 2048 + t) * 64;
    qo[dp]      = f2bf(0.125f * (x1 * cs - x2 * sn));
    qo[dp + 32] = f2bf(0.125f * (x1 * sn + x2 * cs));

    u32 kk = *(const u32*)(row + 1024 + h * 64 + 2 * dp);
    x1 = bf2f((u16)kk); x2 = bf2f((u16)(kk >> 16));
    u16* ko = KR + ((size_t)bh * 2048 + t) * 64;
    ko[dp]      = f2bf(x1 * cs - x2 * sn);
    ko[dp + 32] = f2bf(x1 * sn + x2 * cs);
  }

  __shared__ u16 vld[64][72];
#pragma unroll
  for (int it = 0; it < 2; ++it) {
    int slot = it * 256 + tid;
    int tl = slot >> 3, ch = slot & 7;
    int tok = b * 2048 + t0 + tl;
    uint4 v = *(const uint4*)(qkv + (size_t)tok * 3072 + 2048 + h * 64 + ch * 8);
    *(uint4*)&vld[tl][ch * 8] = v;
  }
  __syncthreads();
#pragma unroll
  for (int it = 0; it < 2; ++it) {
    int slot = it * 256 + tid;
    int d = slot >> 3, tch = slot & 7;  // keys tch*8 .. tch*8+7
    u16 tmp[8];
#pragma unroll
    for (int i = 0; i < 8; ++i) tmp[i] = vld[tch * 8 + i][d];
    // perm: kk = tch*8+i -> pos = 32*s2 + 8*g + 4*b + j
    int s2 = tch >> 2, bb = (tch >> 1) & 1;
    int g0 = (2 * tch) & 3;            // i in [0,4)
    int g1 = (2 * tch + 1) & 3;        // i in [4,8)
    u16* vout = VT + ((size_t)bh * 64 + d) * 2048 + t0 + s2 * 32 + bb * 4;
    u32x2 lo = { (u32)tmp[0] | ((u32)tmp[1] << 16), (u32)tmp[2] | ((u32)tmp[3] << 16) };
    u32x2 hi = { (u32)tmp[4] | ((u32)tmp[5] << 16), (u32)tmp[6] | ((u32)tmp[7] << 16) };
    *(u32x2*)(vout + g0 * 8) = lo;
    *(u32x2*)(vout + g1 * 8) = hi;
  }
}

// ---- causal flash attention v5: uniform-work 2-wave blocks -----------------
// 512 blocks x 128 threads. Block = bh + pair of 64-row q-tiles (tA=31-i,
// tB=i) processed SEQUENTIALLY (phase A then B) -> every block does exactly
// ntA+ntB = 33 key-tile steps: placement-proof balance (R6 lesson: dispatch
// placement is undefined, so make all blocks identical). Each wave owns 32 q
// rows per phase -> K/V LDS reads amortized over 32 q (R6's halving, kept).
// KVBLK=64 dbuf LDS (32KB) via global_load_lds, source-side XOR swizzle,
// key-permuted VT (single b128 V-frags, 0 conflicts measured in R6).
// Prefetch crosses the phase boundary. defer-max (T13), cvt_pk, per-lane
// partial l, setprio (T5).
__global__ __launch_bounds__(128) void k_attn(const u16* __restrict__ QR,
                                              const u16* __restrict__ KR,
                                              const u16* __restrict__ VT,
                                              u16* __restrict__ AO) {
  int tid = threadIdx.x;
  int w = tid >> 6, lane = tid & 63;   // w in {0,1}
  int g = lane >> 4, l15 = lane & 15;
  int l7 = l15 & 7;

  int idx = blockIdx.x;              // 0..511
  int bh = idx & 31;                 // bh mod 8 = XCD slot -> 4 bh per XCD
  int i  = idx >> 5;                 // pair 0..15
  int ta = 31 - i, tb = i;           // 64-row q-tile indices (heavy, light)
  int ntA = ta + 1, ntB = tb + 1;    // key tiles; ntA + ntB = 33 (uniform)
  int b = bh >> 4, h = bh & 15;

  const u16* Kg = KR + (size_t)bh * 2048 * 64;
  const u16* Vg = VT + (size_t)bh * 64 * 2048;

  __shared__ u16 Klds[2][64 * 64];   // 8KB/buf: [key][64 d], chunk-swizzled
  __shared__ u16 Vlds[2][64 * 64];   // 8KB/buf: [d][64 key perm], swizzled

  // hoisted LDS read constants
  int kx0 = ((g ^ l7) << 4);
  int kx1 = (((4 + g) ^ l7) << 4);

  // staging: 128 threads cover 64 rows x 8 chunks in 4 issues (K and V each)
  int rstg = lane >> 3;              // 0..7
  int cswz = (lane & 7) ^ rstg;      // pre-swizzled source chunk

  auto stage = [&](int kt, int buf) {
#pragma unroll
    for (int j = 0; j < 4; ++j) {
      int rb = j * 16 + w * 8;       // 0,8,16,..,56
      int r = rb + rstg;
      gload16(Kg + (size_t)(kt * 64 + r) * 64 + cswz * 8, &Klds[buf][rb * 64]);
      gload16(Vg + (size_t)r * 2048 + kt * 64 + cswz * 8, &Vlds[buf][rb * 64]);
    }
  };

  int cur = 0;
  stage(0, 0);
  __syncthreads();

  auto phase = [&](int tile, int nt, int hasNext) {
    int q0 = tile * 64 + w * 32;     // wave's 32 q rows
    bf16x8 qf[2][2];
#pragma unroll
    for (int qi = 0; qi < 2; ++qi) {
      const u16* Qr = QR + ((size_t)bh * 2048 + q0 + 16 * qi + l15) * 64 + 8 * g;
      qf[qi][0] = *(const bf16x8*)(Qr);
      qf[qi][1] = *(const bf16x8*)(Qr + 32);
    }
    f32x4 o[2][4] = {};
    float m0 = -1e30f, l0 = 0.f, m1 = -1e30f, l1 = 0.f;

    for (int kt = 0; kt < nt; ++kt) {
      int s = kt + 1;
      if (s < nt) stage(s, cur ^ 1);           // prefetch next key-tile
      else if (hasNext) stage(0, cur ^ 1);     // cross into next phase
      const char* Kb = (const char*)&Klds[cur][0];
      const char* Vb = (const char*)&Vlds[cur][0];

      // K fragments (shared by both q-frags)
      bf16x8 kf0[4], kf1[4];
#pragma unroll
      for (int blk = 0; blk < 4; ++blk) {
        const char* kb = Kb + blk * 2048 + l15 * 128;
        kf0[blk] = *(const bf16x8*)(kb + kx0);
        kf1[blk] = *(const bf16x8*)(kb + kx1);
      }
      bf16x8 pb[2][2];
      bool domask = (kt == nt - 1);
      int tkb = kt * 64 + 4 * g;
#pragma unroll
      for (int qi = 0; qi < 2; ++qi) {
        float& m = qi ? m1 : m0;
        float& l = qi ? l1 : l0;
        f32x4 sb[4];
        __builtin_amdgcn_s_setprio(1);
#pragma unroll
        for (int blk = 0; blk < 4; ++blk) {
          f32x4 z = { 0.f, 0.f, 0.f, 0.f };
          z = mfma16(kf0[blk], qf[qi][0], z);
          sb[blk] = mfma16(kf1[blk], qf[qi][1], z);
        }
        __builtin_amdgcn_s_setprio(0);
        if (domask) {
          int qa = q0 + 16 * qi + l15;
#pragma unroll
          for (int blk = 0; blk < 4; ++blk)
#pragma unroll
            for (int j = 0; j < 4; ++j) {
              int tk = tkb + blk * 16 + j;
              if (tk > qa) sb[blk][j] = -1e30f;
            }
        }
        // online softmax with defer-max
        float mx = fmaxf(fmaxf(fmaxf(sb[0][0], sb[0][1]), fmaxf(sb[0][2], sb[0][3])),
                         fmaxf(fmaxf(sb[1][0], sb[1][1]), fmaxf(sb[1][2], sb[1][3])));
        mx = fmaxf(mx, fmaxf(fmaxf(fmaxf(sb[2][0], sb[2][1]), fmaxf(sb[2][2], sb[2][3])),
                             fmaxf(fmaxf(sb[3][0], sb[3][1]), fmaxf(sb[3][2], sb[3][3]))));
        mx = fmaxf(mx, __shfl_xor(mx, 16));
        mx = fmaxf(mx, __shfl_xor(mx, 32));
        if (!__all(mx <= m + 8.0f)) {
          float mnew = fmaxf(m, mx);
          float a = __builtin_amdgcn_exp2f((m - mnew) * 1.44269504f);
          l *= a;
#pragma unroll
          for (int d = 0; d < 4; ++d) o[qi][d] *= a;
          m = mnew;
        }
        float em = m * 1.44269504f;
        float p[4][4];
        float ps = 0.f;
#pragma unroll
        for (int blk = 0; blk < 4; ++blk)
#pragma unroll
          for (int j = 0; j < 4; ++j) {
            float pv = __builtin_amdgcn_exp2f(__builtin_fmaf(sb[blk][j], 1.44269504f, -em));
            p[blk][j] = pv;
            ps += pv;
          }
        l += ps;
#pragma unroll
        for (int s2 = 0; s2 < 2; ++s2) {
          u32x4 pw = { cvtpk(p[2 * s2][0], p[2 * s2][1]),
                       cvtpk(p[2 * s2][2], p[2 * s2][3]),
                       cvtpk(p[2 * s2 + 1][0], p[2 * s2 + 1][1]),
                       cvtpk(p[2 * s2 + 1][2], p[2 * s2 + 1][3]) };
          pb[qi][s2] = __builtin_bit_cast(bf16x8, pw);
        }
      }
      // PV: V frags (key-permuted -> single b128 each), shared by both q-frags
      __builtin_amdgcn_s_setprio(1);
#pragma unroll
      for (int s2 = 0; s2 < 2; ++s2) {
        int vx = s2 ? kx1 : kx0;
#pragma unroll
        for (int dblk = 0; dblk < 4; ++dblk) {
          bf16x8 va = *(const bf16x8*)(Vb + dblk * 2048 + l15 * 128 + vx);
          o[0][dblk] = mfma16(va, pb[0][s2], o[0][dblk]);
          o[1][dblk] = mfma16(va, pb[1][s2], o[1][dblk]);
        }
      }
      __builtin_amdgcn_s_setprio(0);

      __syncthreads();
      cur ^= 1;
    }

    // phase epilogue: write O
#pragma unroll
    for (int qi = 0; qi < 2; ++qi) {
      float l = qi ? l1 : l0;
      float lt = l + __shfl_xor(l, 16);
      lt += __shfl_xor(lt, 32);
      float inv = 1.0f / lt;
      u16* orow = AO + ((size_t)b * 2048 + q0 + 16 * qi + l15) * 1024 + h * 64 + 4 * g;
#pragma unroll
      for (int dblk = 0; dblk < 4; ++dblk) {
        u32x2 ov = { cvtpk(o[qi][dblk][0] * inv, o[qi][dblk][1] * inv),
                     cvtpk(o[qi][dblk][2] * inv, o[qi][dblk][3] * inv) };
        *(u32x2*)(orow + dblk * 16) = ov;
      }
    }
  };

  phase(ta, ntA, 1);   // heavy tile first; last step prefetches B's tile 0
  phase(tb, ntB, 0);
}

// ---- launcher ---------------------------------------------------------------
extern "C" void kernel_launch(void* const* d_in, const int* in_sizes, int n_in,
                              void* d_out, int out_size, void* d_ws, size_t ws_size,
                              hipStream_t stream) {
  (void)in_sizes; (void)n_in; (void)out_size; (void)ws_size;
  const float* x     = (const float*)d_in[0];
  const float* Wqkv  = (const float*)d_in[1];
  const float* bqkv  = (const float*)d_in[2];
  const float* Wproj = (const float*)d_in[3];
  const float* bproj = (const float*)d_in[4];
  const int*   pos   = (const int*)d_in[5];

  char* ws = (char*)d_ws;
  u16*   XB     = (u16*)(ws + 0);
  u16*   WQKVT  = (u16*)(ws + 8388608);
  u16*   WPROJT = (u16*)(ws + 14680064);
  u16*   QKV    = (u16*)(ws + 16777216);
  u16*   QR     = (u16*)(ws + 41943040);
  u16*   KR     = (u16*)(ws + 50331648);
  u16*   VT     = (u16*)(ws + 58720256);
  u16*   AO     = (u16*)(ws + 67108864);
  float* SIN    = (float*)(ws + 75497472);
  float* COS    = (float*)(ws + 75759616);

  k_cvt_bf16<<<2048, 256, 0, stream>>>(x, XB);
  k_transpose_cvt<<<32 * 96, 256, 0, stream>>>(Wqkv, WQKVT, 3072);
  k_transpose_cvt<<<32 * 32, 256, 0, stream>>>(Wproj, WPROJT, 1024);
  k_tables<<<256, 256, 0, stream>>>(pos, SIN, COS);
  k_gemm<3072, false><<<32 * 24, 256, 0, stream>>>(XB, WQKVT, bqkv, QKV);
  k_rope<<<32 * 32, 256, 0, stream>>>(QKV, SIN, COS, QR, KR, VT);
  k_attn<<<512, 128, 0, stream>>>(QR, KR, VT, AO);
  k_gemm<1024, true><<<32 * 8, 256, 0, stream>>>(AO, WPROJT, bproj, d_out);
}

// Round 8
// 127.003 us; speedup vs baseline: 1.1280x; 1.1280x over previous
//
#include <hip/hip_runtime.h>
#include <hip/hip_bf16.h>
#include <stdint.h>

#define DEV __device__ __forceinline__

typedef unsigned short u16;
typedef unsigned int   u32;
typedef __attribute__((ext_vector_type(8))) short bf16x8;   // 8 bf16 = 4 VGPRs
typedef __attribute__((ext_vector_type(4))) float f32x4;
typedef __attribute__((ext_vector_type(4))) u32   u32x4;
typedef __attribute__((ext_vector_type(2))) u32   u32x2;

// ---- numeric helpers -------------------------------------------------------
DEV u16 f2bf(float f) {            // RNE f32 -> bf16
  u32 u = __builtin_bit_cast(u32, f);
  u = (u + 0x7fffu + ((u >> 16) & 1u)) >> 16;
  return (u16)u;
}
DEV float bf2f(u16 h) { return __builtin_bit_cast(float, (u32)h << 16); }
DEV u32 pk2(float a, float b) {    // pack 2 f32 -> 2 bf16 in one u32 (RNE)
  u32 x = __builtin_bit_cast(u32, a), y = __builtin_bit_cast(u32, b);
  x = (x + 0x7fffu + ((x >> 16) & 1u)) >> 16;
  y = (y + 0x7fffu + ((y >> 16) & 1u)) >> 16;
  return x | (y << 16);
}
DEV u32 cvtpk(float lo, float hi) {  // 1-instr RNE pack (same semantics as pk2)
  u32 r;
  asm("v_cvt_pk_bf16_f32 %0, %1, %2" : "=v"(r) : "v"(lo), "v"(hi));
  return r;
}
DEV f32x4 mfma16(bf16x8 a, bf16x8 b, f32x4 c) {
  return __builtin_amdgcn_mfma_f32_16x16x32_bf16(a, b, c, 0, 0, 0);
}
DEV void gload16(const void* g, void* l) {   // global -> LDS direct, 16B/lane
  __builtin_amdgcn_global_load_lds(
      (const __attribute__((address_space(1))) void*)g,
      (__attribute__((address_space(3))) void*)l, 16, 0, 0);
}

// ---- problem constants -----------------------------------------------------
// B=2 T=2048 DIM=1024 HEADS=16 HEAD_DIM=64; tokens = 4096
// workspace layout (bytes):
//  XB      0         x as bf16            [4096][1024]
//  WQKVT   8388608   Wqkv^T bf16          [3072][1024]
//  WPROJT  14680064  Wproj^T bf16         [1024][1024]
//  QKV     16777216  qkv bf16             [4096][3072]
//  QR      41943040  roped*scale Q bf16   [32][2048][64]
//  KR      50331648  roped K bf16         [32][2048][64]
//  VT      58720256  V^T bf16 KEY-PERMUTED [32][64][2048]
//  AO      67108864  attn out bf16        [4096][1024]
//  SIN     75497472  f32 [2048][32]
//  COS     75759616  f32 [2048][32]

// ---- prep kernels ----------------------------------------------------------
__global__ __launch_bounds__(256) void k_cvt_bf16(const float* __restrict__ in,
                                                  u16* __restrict__ out) {
  size_t i = ((size_t)blockIdx.x * 256 + threadIdx.x) * 8;
  float4 a = *(const float4*)(in + i);
  float4 b = *(const float4*)(in + i + 4);
  u32x4 o = { pk2(a.x, a.y), pk2(a.z, a.w), pk2(b.x, b.y), pk2(b.z, b.w) };
  *(u32x4*)(out + i) = o;
}

// W [1024][Ndim] f32 -> WT [Ndim][1024] bf16 (coalesced both sides via LDS)
__global__ __launch_bounds__(256) void k_transpose_cvt(const float* __restrict__ W,
                                                       u16* __restrict__ WT,
                                                       int Ndim) {
  int bk = blockIdx.x & 31;        // K/32 = 32
  int bn = blockIdx.x >> 5;
  int k0 = bk * 32, n0 = bn * 32;
  __shared__ float t[32][33];
  int tx = threadIdx.x & 31, ty = threadIdx.x >> 5; // ty 0..7
#pragma unroll
  for (int i = 0; i < 4; ++i)
    t[ty + 8 * i][tx] = W[(size_t)(k0 + ty + 8 * i) * Ndim + n0 + tx];
  __syncthreads();
#pragma unroll
  for (int i = 0; i < 4; ++i) {
    int n = ty + 8 * i;
    WT[(size_t)(n0 + n) * 1024 + k0 + tx] = f2bf(t[tx][n]);
  }
}

__global__ __launch_bounds__(256) void k_tables(const int* __restrict__ posp,
                                                float* __restrict__ sint,
                                                float* __restrict__ cost) {
  int i = blockIdx.x * 256 + threadIdx.x;   // 65536 = 2048*32
  int t = i >> 5, d = i & 31;
  float theta = exp2f(-(float)d * (13.2877123795494f / 32.0f));
  float ang = (float)(posp[0] + t) * theta;
  sint[i] = sinf(ang);
  cost[i] = cosf(ang);
}

// ---- GEMM: C[4096][N] = A[4096][1024] @ BT^T + bias ------------------------
// 128x128 tile, BK=32, 4 waves (2x2 of 64x64), mfma 16x16x32 bf16.
// Staging: global_load_lds width=16, linear LDS dest, swizzle applied on the
// GLOBAL source address (rule #21). Reads use the same XOR chunk swizzle.
template <int N, bool OUTF32>
__global__ __launch_bounds__(256, 3) void k_gemm(const u16* __restrict__ A,
                                                 const u16* __restrict__ BT,
                                                 const float* __restrict__ bias,
                                                 void* __restrict__ Cout) {
  constexpr int K = 1024;
  int bm = blockIdx.x & 31;             // M/128 = 32
  int bn = blockIdx.x >> 5;
  int m0 = bm * 128, n0 = bn * 128;
  int tid = threadIdx.x, lane = tid & 63, w = tid >> 6;
  int g = lane >> 4, l15 = lane & 15;
  int wr = w >> 1, wc = w & 1;

  __shared__ u16 Alds[128 * 32];
  __shared__ u16 Blds[128 * 32];

  f32x4 acc[4][4] = {};

  int rowW = w * 16 + (lane >> 2);
  int cSrc = (lane & 3) ^ ((lane >> 3) & 3);
  const u16* Ag0 = A  + (size_t)(m0 + rowW) * K + cSrc * 8;
  const u16* Ag1 = A  + (size_t)(m0 + 64 + rowW) * K + cSrc * 8;
  const u16* Bg0 = BT + (size_t)(n0 + rowW) * K + cSrc * 8;
  const u16* Bg1 = BT + (size_t)(n0 + 64 + rowW) * K + cSrc * 8;
  char* AldsW0 = (char*)Alds + w * 1024;          // + lane*16 by HW
  char* AldsW1 = (char*)Alds + 4096 + w * 1024;
  char* BldsW0 = (char*)Blds + w * 1024;
  char* BldsW1 = (char*)Blds + 4096 + w * 1024;

  for (int k0 = 0; k0 < K; k0 += 32) {
    gload16(Ag0 + k0, AldsW0);
    gload16(Ag1 + k0, AldsW1);
    gload16(Bg0 + k0, BldsW0);
    gload16(Bg1 + k0, BldsW1);
    __syncthreads();                    // drains vmcnt (compiler-inserted)
    bf16x8 af[4], bf_[4];
#pragma unroll
    for (int m = 0; m < 4; ++m) {
      int r = wr * 64 + m * 16 + l15;
      af[m] = *(const bf16x8*)((const char*)Alds + r * 64 + ((g ^ ((r >> 1) & 3)) << 4));
    }
#pragma unroll
    for (int n = 0; n < 4; ++n) {
      int r = wc * 64 + n * 16 + l15;
      bf_[n] = *(const bf16x8*)((const char*)Blds + r * 64 + ((g ^ ((r >> 1) & 3)) << 4));
    }
#pragma unroll
    for (int m = 0; m < 4; ++m)
#pragma unroll
      for (int n = 0; n < 4; ++n)
        acc[m][n] = mfma16(af[m], bf_[n], acc[m][n]);
    __syncthreads();
  }

#pragma unroll
  for (int m = 0; m < 4; ++m) {
    int rowb = m0 + wr * 64 + m * 16 + 4 * g;
#pragma unroll
    for (int n = 0; n < 4; ++n) {
      int col = n0 + wc * 64 + n * 16 + l15;
      float bv = bias[col];
#pragma unroll
      for (int j = 0; j < 4; ++j) {
        float v = acc[m][n][j] + bv;
        if constexpr (OUTF32)
          ((float*)Cout)[(size_t)(rowb + j) * N + col] = v;
        else
          ((u16*)Cout)[(size_t)(rowb + j) * N + col] = f2bf(v);
      }
    }
  }
}

// ---- RoPE + head reshape + V transpose (key-permuted for PV b128 frags) ----
// VT key order within each 64-tile: key kk = 32*s2 + 16*b + 4*g + j stored at
// pos = 32*s2 + 8*g + 4*b + j, so each PV A-fragment (8 keys) is contiguous.
__global__ __launch_bounds__(256) void k_rope(const u16* __restrict__ qkv,
                                              const float* __restrict__ sint,
                                              const float* __restrict__ cost,
                                              u16* __restrict__ QR,
                                              u16* __restrict__ KR,
                                              u16* __restrict__ VT) {
  int bid = blockIdx.x;
  int bh = bid >> 5;                 // T/64 = 32 blocks per (b,h)
  int t0 = (bid & 31) * 64;
  int b = bh >> 4, h = bh & 15;
  int tid = threadIdx.x;

  int dp = tid & 31;
  int tt0 = tid >> 5;                 // 0..7
#pragma unroll
  for (int r = 0; r < 8; ++r) {
    int tl = r * 8 + tt0;
    int t = t0 + tl;
    int tok = b * 2048 + t;
    const u16* row = qkv + (size_t)tok * 3072;
    float sn = sint[t * 32 + dp], cs = cost[t * 32 + dp];

    u32 qq = *(const u32*)(row + h * 64 + 2 * dp);
    float x1 = bf2f((u16)qq), x2 = bf2f((u16)(qq >> 16));
    u16* qo = QR + ((size_t)bh * 2048 + t) * 64;
    qo[dp]      = f2bf(0.125f * (x1 * cs - x2 * sn));
    qo[dp + 32] = f2bf(0.125f * (x1 * sn + x2 * cs));

    u32 kk = *(const u32*)(row + 1024 + h * 64 + 2 * dp);
    x1 = bf2f((u16)kk); x2 = bf2f((u16)(kk >> 16));
    u16* ko = KR + ((size_t)bh * 2048 + t) * 64;
    ko[dp]      = f2bf(x1 * cs - x2 * sn);
    ko[dp + 32] = f2bf(x1 * sn + x2 * cs);
  }

  __shared__ u16 vld[64][72];
#pragma unroll
  for (int it = 0; it < 2; ++it) {
    int slot = it * 256 + tid;
    int tl = slot >> 3, ch = slot & 7;
    int tok = b * 2048 + t0 + tl;
    uint4 v = *(const uint4*)(qkv + (size_t)tok * 3072 + 2048 + h * 64 + ch * 8);
    *(uint4*)&vld[tl][ch * 8] = v;
  }
  __syncthreads();
#pragma unroll
  for (int it = 0; it < 2; ++it) {
    int slot = it * 256 + tid;
    int d = slot >> 3, tch = slot & 7;  // keys tch*8 .. tch*8+7
    u16 tmp[8];
#pragma unroll
    for (int i = 0; i < 8; ++i) tmp[i] = vld[tch * 8 + i][d];
    // perm: kk = tch*8+i -> pos = 32*s2 + 8*g + 4*b + j
    int s2 = tch >> 2, bb = (tch >> 1) & 1;
    int g0 = (2 * tch) & 3;            // i in [0,4)
    int g1 = (2 * tch + 1) & 3;        // i in [4,8)
    u16* vout = VT + ((size_t)bh * 64 + d) * 2048 + t0 + s2 * 32 + bb * 4;
    u32x2 lo = { (u32)tmp[0] | ((u32)tmp[1] << 16), (u32)tmp[2] | ((u32)tmp[3] << 16) };
    u32x2 hi = { (u32)tmp[4] | ((u32)tmp[5] << 16), (u32)tmp[6] | ((u32)tmp[7] << 16) };
    *(u32x2*)(vout + g0 * 8) = lo;
    *(u32x2*)(vout + g1 * 8) = hi;
  }
}

// ---- causal flash attention v6: R6 engine + placement-matched balance ------
// 512 blocks x 256 thr (4 waves x 32q = 128-q tile). Placement rule observed
// across R5/R6: blocks i and i+256 share a CU. Mapping u=idx>>5,
// tile = u<8 ? 15-u : u-8 makes every CU's two blocks sum to 34 steps
// (tileA+tileB=15), heavy half dispatched first. 32q/wave K/V amortization
// (R6, ~0.94us/step), key-permuted VT single-b128 V frags (0 conflicts),
// KVBLK=64 dbuf LDS (32KB) via global_load_lds + source-side XOR swizzle.
// defer-max now also skips the 2 cross-lane __shfl_xor (common case),
// cvt_pk, per-lane partial l, setprio (T5), per-wave masked-tile skip.
__global__ __launch_bounds__(256, 2) void k_attn(const u16* __restrict__ QR,
                                                 const u16* __restrict__ KR,
                                                 const u16* __restrict__ VT,
                                                 u16* __restrict__ AO) {
  int tid = threadIdx.x;
  int w = tid >> 6, lane = tid & 63;
  int g = lane >> 4, l15 = lane & 15;
  int l7 = l15 & 7;

  int idx = blockIdx.x;              // 0..511
  int bh = idx & 31;                 // bh mod 8 = XCD slot -> 4 bh per XCD
  int u = idx >> 5;                  // 0..15
  int tile = (u < 8) ? (15 - u) : (u - 8);   // CU pair sums to 15
  int nt = 2 * tile + 2;             // 64-key tiles
  int b = bh >> 4, h = bh & 15;
  int q0 = tile * 128 + w * 32;      // wave's 32 q rows

  const u16* Kg = KR + (size_t)bh * 2048 * 64;
  const u16* Vg = VT + (size_t)bh * 64 * 2048;

  __shared__ u16 Klds[2][64 * 64];   // 8KB/buf: [key][64 d], chunk-swizzled
  __shared__ u16 Vlds[2][64 * 64];   // 8KB/buf: [d][64 key perm], swizzled

  bf16x8 qf[2][2];
#pragma unroll
  for (int qi = 0; qi < 2; ++qi) {
    const u16* Qr = QR + ((size_t)bh * 2048 + q0 + 16 * qi + l15) * 64 + 8 * g;
    qf[qi][0] = *(const bf16x8*)(Qr);
    qf[qi][1] = *(const bf16x8*)(Qr + 32);
  }

  f32x4 o[2][4] = {};
  float m0 = -1e30f, l0 = 0.f, m1 = -1e30f, l1 = 0.f;

  // hoisted LDS read constants (K rows and V rows share (R&7)==l7)
  int kx0 = ((g ^ l7) << 4);
  int kx1 = (((4 + g) ^ l7) << 4);

  // staging: 256 threads cover 64 rows x 8 chunks in 2 issues (K and V each)
  int rstg = lane >> 3;              // 0..7
  int cswz = (lane & 7) ^ rstg;      // pre-swizzled source chunk

  auto stage = [&](int kt, int buf) {
#pragma unroll
    for (int j = 0; j < 2; ++j) {
      int r = j * 32 + w * 8 + rstg;
      gload16(Kg + (size_t)(kt * 64 + r) * 64 + cswz * 8,
              &Klds[buf][(j * 32 + w * 8) * 64]);
      gload16(Vg + (size_t)r * 2048 + kt * 64 + cswz * 8,
              &Vlds[buf][(j * 32 + w * 8) * 64]);
    }
  };

  stage(0, 0);
  __syncthreads();
  int cur = 0;

  for (int t = 0; t < nt; ++t) {
    if (t + 1 < nt) stage(t + 1, cur ^ 1);   // async prefetch next tile
    const char* Kb = (const char*)&Klds[cur][0];
    const char* Vb = (const char*)&Vlds[cur][0];

    if (t * 64 <= q0 + 31) {         // wave has unmasked keys in this tile
      // K fragments (shared by both q-frags)
      bf16x8 kf0[4], kf1[4];
#pragma unroll
      for (int blk = 0; blk < 4; ++blk) {
        const char* kb = Kb + blk * 2048 + l15 * 128;
        kf0[blk] = *(const bf16x8*)(kb + kx0);
        kf1[blk] = *(const bf16x8*)(kb + kx1);
      }
      bf16x8 pb[2][2];
      bool domask = (t >= nt - 2);
      int tkb = t * 64 + 4 * g;
#pragma unroll
      for (int qi = 0; qi < 2; ++qi) {
        float& m = qi ? m1 : m0;
        float& l = qi ? l1 : l0;
        f32x4 sb[4];
        __builtin_amdgcn_s_setprio(1);
#pragma unroll
        for (int blk = 0; blk < 4; ++blk) {
          f32x4 z = { 0.f, 0.f, 0.f, 0.f };
          z = mfma16(kf0[blk], qf[qi][0], z);
          sb[blk] = mfma16(kf1[blk], qf[qi][1], z);
        }
        __builtin_amdgcn_s_setprio(0);
        if (domask) {
          int qa = q0 + 16 * qi + l15;
#pragma unroll
          for (int blk = 0; blk < 4; ++blk)
#pragma unroll
            for (int j = 0; j < 4; ++j) {
              int tk = tkb + blk * 16 + j;
              if (tk > qa) sb[blk][j] = -1e30f;
            }
        }
        // online softmax: lane-local max; cross-lane reduce + rescale only
        // when the defer-max threshold trips (uncommon)
        float mx = fmaxf(fmaxf(fmaxf(sb[0][0], sb[0][1]), fmaxf(sb[0][2], sb[0][3])),
                         fmaxf(fmaxf(sb[1][0], sb[1][1]), fmaxf(sb[1][2], sb[1][3])));
        mx = fmaxf(mx, fmaxf(fmaxf(fmaxf(sb[2][0], sb[2][1]), fmaxf(sb[2][2], sb[2][3])),
                             fmaxf(fmaxf(sb[3][0], sb[3][1]), fmaxf(sb[3][2], sb[3][3]))));
        if (!__all(mx <= m + 8.0f)) {
          mx = fmaxf(mx, __shfl_xor(mx, 16));
          mx = fmaxf(mx, __shfl_xor(mx, 32));
          float mnew = fmaxf(m, mx);
          float a = __builtin_amdgcn_exp2f((m - mnew) * 1.44269504f);
          l *= a;
#pragma unroll
          for (int d = 0; d < 4; ++d) o[qi][d] *= a;
          m = mnew;
        }
        float em = m * 1.44269504f;
        float p[4][4];
        float ps = 0.f;
#pragma unroll
        for (int blk = 0; blk < 4; ++blk)
#pragma unroll
          for (int j = 0; j < 4; ++j) {
            float pv = __builtin_amdgcn_exp2f(__builtin_fmaf(sb[blk][j], 1.44269504f, -em));
            p[blk][j] = pv;
            ps += pv;
          }
        l += ps;
#pragma unroll
        for (int s2 = 0; s2 < 2; ++s2) {
          u32x4 pw = { cvtpk(p[2 * s2][0], p[2 * s2][1]),
                       cvtpk(p[2 * s2][2], p[2 * s2][3]),
                       cvtpk(p[2 * s2 + 1][0], p[2 * s2 + 1][1]),
                       cvtpk(p[2 * s2 + 1][2], p[2 * s2 + 1][3]) };
          pb[qi][s2] = __builtin_bit_cast(bf16x8, pw);
        }
      }
      // PV: V frags (key-permuted -> single b128 each), shared by both q-frags
      __builtin_amdgcn_s_setprio(1);
#pragma unroll
      for (int s2 = 0; s2 < 2; ++s2) {
        int vx = s2 ? kx1 : kx0;
#pragma unroll
        for (int dblk = 0; dblk < 4; ++dblk) {
          bf16x8 va = *(const bf16x8*)(Vb + dblk * 2048 + l15 * 128 + vx);
          o[0][dblk] = mfma16(va, pb[0][s2], o[0][dblk]);
          o[1][dblk] = mfma16(va, pb[1][s2], o[1][dblk]);
        }
      }
      __builtin_amdgcn_s_setprio(0);
    }

    __syncthreads();
    cur ^= 1;
  }

#pragma unroll
  for (int qi = 0; qi < 2; ++qi) {
    float l = qi ? l1 : l0;
    float lt = l + __shfl_xor(l, 16);
    lt += __shfl_xor(lt, 32);
    float inv = 1.0f / lt;
    u16* orow = AO + ((size_t)b * 2048 + q0 + 16 * qi + l15) * 1024 + h * 64 + 4 * g;
#pragma unroll
    for (int dblk = 0; dblk < 4; ++dblk) {
      u32x2 ov = { cvtpk(o[qi][dblk][0] * inv, o[qi][dblk][1] * inv),
                   cvtpk(o[qi][dblk][2] * inv, o[qi][dblk][3] * inv) };
      *(u32x2*)(orow + dblk * 16) = ov;
    }
  }
}

// ---- launcher ---------------------------------------------------------------
extern "C" void kernel_launch(void* const* d_in, const int* in_sizes, int n_in,
                              void* d_out, int out_size, void* d_ws, size_t ws_size,
                              hipStream_t stream) {
  (void)in_sizes; (void)n_in; (void)out_size; (void)ws_size;
  const float* x     = (const float*)d_in[0];
  const float* Wqkv  = (const float*)d_in[1];
  const float* bqkv  = (const float*)d_in[2];
  const float* Wproj = (const float*)d_in[3];
  const float* bproj = (const float*)d_in[4];
  const int*   pos   = (const int*)d_in[5];

  char* ws = (char*)d_ws;
  u16*   XB     = (u16*)(ws + 0);
  u16*   WQKVT  = (u16*)(ws + 8388608);
  u16*   WPROJT = (u16*)(ws + 14680064);
  u16*   QKV    = (u16*)(ws + 16777216);
  u16*   QR     = (u16*)(ws + 41943040);
  u16*   KR     = (u16*)(ws + 50331648);
  u16*   VT     = (u16*)(ws + 58720256);
  u16*   AO     = (u16*)(ws + 67108864);
  float* SIN    = (float*)(ws + 75497472);
  float* COS    = (float*)(ws + 75759616);

  k_cvt_bf16<<<2048, 256, 0, stream>>>(x, XB);
  k_transpose_cvt<<<32 * 96, 256, 0, stream>>>(Wqkv, WQKVT, 3072);
  k_transpose_cvt<<<32 * 32, 256, 0, stream>>>(Wproj, WPROJT, 1024);
  k_tables<<<256, 256, 0, stream>>>(pos, SIN, COS);
  k_gemm<3072, false><<<32 * 24, 256, 0, stream>>>(XB, WQKVT, bqkv, QKV);
  k_rope<<<32 * 32, 256, 0, stream>>>(QKV, SIN, COS, QR, KR, VT);
  k_attn<<<512, 256, 0, stream>>>(QR, KR, VT, AO);
  k_gemm<1024, true><<<32 * 8, 256, 0, stream>>>(AO, WPROJT, bproj, d_out);
}